// Round 3
// baseline (607.267 us; speedup 1.0000x reference)
//
#include <hip/hip_runtime.h>

// GaussianSoftmax: out[b,n,m] = softmax_m( exp( exp(-max(||x_n-x_m||^2,0)/sigma) ) )
// X: [8, 4096, 16] fp32, sigma: [1], out: [8, 4096, 4096] fp32 (512 MiB).
//
// R14: MFMA rewrite. R13 counters showed dur_us = harness fill (346.7 us,
// untouchable) + pack (~10) + gs (~205). gs's 205 ~= SUM of {write 87,
// L2-read 66, VALU 65} -> attack VALU (16 fma/elem dot -> matrix pipe) and
// L2 traffic (TN=4 -> BM=16 rows/block: 2.28 GB -> 0.5 GB).
//
// Design:
//  - X packed as bf16 hi/lo split (x = hi + lo exactly to ~2^-17 rel):
//    Xp[b][m] = 64 B: per k-group g(0..3): [hi f4g..4g+3 | lo f4g..4g+3].
//    inner = mfma(A,B1) + mfma(A,B2) where B2 = dword-half swap of B1:
//    = (hiA.hiB + loA.loB) + (hiA.loB + loA.hiB). Dropped loA.loB is
//    included (harmless); error from bf16(lo) residual ~1e-7 on out.
//    Slot->k mapping is irrelevant: A and B use IDENTICAL per-lane packing,
//    MFMA pairs slots positionally (A/B layouts symmetric), and the inner
//    product is invariant under any common k-permutation.
//  - mfma(A=m-rows, B=n-rows) -> C/D layout (m89-verified): col=lane&15=n
//    (lane's softmax row, CONSTANT), row=4*(lane>>4)+reg = 4 consecutive m.
//    So: e stays in VGPRs (16 tiles x f32x4 = 64 VGPR, no LDS staging, no
//    bf16 pack), row-sum = 2 shfl_xor + 1 KiB LDS cross-wave, store = one
//    float4 nt-store per tile per lane (16 rows x 64 B contiguous per inst).
//  - Block = 16 waves x BM=16 rows x full 4096 cols; wave owns 256 cols.
//    sqn[n] = sqm[n0+lane&15] (rows are also columns -> no q loads at all).

typedef float v4f __attribute__((ext_vector_type(4)));
typedef short bf8 __attribute__((ext_vector_type(8)));

constexpr int Bn  = 8;
constexpr int N   = 4096;
constexpr int F   = 16;
constexpr int BM  = 16;           // output rows per block
constexpr int BLK = 1024;         // 16 waves
constexpr int NW  = BLK / 64;     // 16 waves
constexpr int TPW = (N / 16) / NW; // 16 tiles (of 16 cols) per wave

__device__ __forceinline__ unsigned short f2bf(float x) {   // RNE
    unsigned int u = __float_as_uint(x);
    unsigned int r = (u + 0x7FFFu + ((u >> 16) & 1u)) >> 16;
    return (unsigned short)r;
}
__device__ __forceinline__ float bf2f(unsigned short h) {
    return __uint_as_float(((unsigned int)h) << 16);
}
__device__ __forceinline__ float uni(float x) {
    return __int_as_float(__builtin_amdgcn_readfirstlane(__float_as_int(x)));
}

__global__ __launch_bounds__(256)
void pack_kernel(const float* __restrict__ X, uint4* __restrict__ Xp,
                 float* __restrict__ sqm) {
    const int b = blockIdx.y;
    const int m = blockIdx.x * 256 + threadIdx.x;
    const float4* src = (const float4*)(X + ((size_t)b * N + m) * F);
    const float4 v0 = src[0], v1 = src[1], v2 = src[2], v3 = src[3];
    const float x[F] = {v0.x, v0.y, v0.z, v0.w, v1.x, v1.y, v1.z, v1.w,
                        v2.x, v2.y, v2.z, v2.w, v3.x, v3.y, v3.z, v3.w};
    float s = 0.f;
    #pragma unroll
    for (int f = 0; f < F; ++f) s = fmaf(x[f], x[f], s);
    sqm[(size_t)b * N + m] = s;

    uint4* dst = Xp + ((size_t)b * N + m) * 4;
    #pragma unroll
    for (int g = 0; g < 4; ++g) {
        unsigned int hi[4], lo[4];
        #pragma unroll
        for (int j = 0; j < 4; ++j) {
            const float xf = x[4 * g + j];
            const unsigned short h = f2bf(xf);
            hi[j] = h;
            lo[j] = f2bf(xf - bf2f(h));
        }
        uint4 c;
        c.x = hi[0] | (hi[1] << 16);
        c.y = hi[2] | (hi[3] << 16);
        c.z = lo[0] | (lo[1] << 16);
        c.w = lo[2] | (lo[3] << 16);
        dst[g] = c;
    }
}

union BfU { uint4 u; bf8 h; };

__global__ __launch_bounds__(BLK)
void gs_mfma(const uint4* __restrict__ Xp, const float* __restrict__ sqm,
             const float* __restrict__ sigma_p, float* __restrict__ out) {
    __shared__ float red[NW][BM];   // 1 KiB

    const int tid  = threadIdx.x;
    const int w    = tid >> 6;
    const int lane = tid & 63;
    const int g    = lane >> 4;
    const int c    = lane & 15;
    const int b    = blockIdx.y;
    const int n0   = blockIdx.x * BM;

    const uint4* Xpb = Xp + (size_t)b * N * 4;
    const float* sqb = sqm + (size_t)b * N;

    // Block-constant B frags (n-side rows n0..n0+15).
    BfU b1; b1.u = Xpb[(size_t)(n0 + c) * 4 + g];
    BfU b2; b2.u = make_uint4(b1.u.z, b1.u.w, b1.u.x, b1.u.y);  // hi<->lo swap

    const float sqn_l = sqb[n0 + c];            // this lane's row norm
    const float nis   = uni(-1.0f / sigma_p[0]);

    v4f e[TPW];
    float psum = 0.f;

    #pragma unroll
    for (int t = 0; t < TPW; ++t) {
        const int m_tile = w * (TPW * 16) + t * 16;
        BfU a; a.u = Xpb[(size_t)(m_tile + c) * 4 + g];

        v4f acc = {0.f, 0.f, 0.f, 0.f};
        acc = __builtin_amdgcn_mfma_f32_16x16x32_bf16(a.h, b1.h, acc, 0, 0, 0);
        acc = __builtin_amdgcn_mfma_f32_16x16x32_bf16(a.h, b2.h, acc, 0, 0, 0);
        // acc[j] = inner(x_{m_tile+4g+j}, x_{n0+c})

        const v4f sm4 = *(const v4f*)(sqb + m_tile + 4 * g);
        v4f ev;
        ev.x = __expf(__expf(fmaxf(fmaf(-2.f, acc.x, sqn_l + sm4.x), 0.f) * nis));
        ev.y = __expf(__expf(fmaxf(fmaf(-2.f, acc.y, sqn_l + sm4.y), 0.f) * nis));
        ev.z = __expf(__expf(fmaxf(fmaf(-2.f, acc.z, sqn_l + sm4.z), 0.f) * nis));
        ev.w = __expf(__expf(fmaxf(fmaf(-2.f, acc.w, sqn_l + sm4.w), 0.f) * nis));
        e[t] = ev;
        psum += (ev.x + ev.y) + (ev.z + ev.w);
    }

    // Row-sum for row n0+c: combine the 4 g-groups, then the 16 waves.
    psum += __shfl_xor(psum, 16, 64);
    psum += __shfl_xor(psum, 32, 64);
    if (lane < 16) red[w][lane] = psum;
    __syncthreads();

    float tot = 0.f;
    #pragma unroll
    for (int w2 = 0; w2 < NW; ++w2) tot += red[w2][c];
    const float inv = 1.0f / tot;

    // Store: lane writes float4 at out[n0+c][m_tile + 4g] per tile.
    float* rowp = out + ((size_t)b * N + n0 + c) * (size_t)N;
    #pragma unroll
    for (int t = 0; t < TPW; ++t) {
        const int m_tile = w * (TPW * 16) + t * 16;
        v4f v = e[t] * inv;
        __builtin_nontemporal_store(v, (v4f*)(rowp + m_tile + 4 * g));
    }
}

extern "C" void kernel_launch(void* const* d_in, const int* in_sizes, int n_in,
                              void* d_out, int out_size, void* d_ws, size_t ws_size,
                              hipStream_t stream) {
    const float* X     = (const float*)d_in[0];
    const float* sigma = (const float*)d_in[1];
    float* out         = (float*)d_out;
    uint4* Xp          = (uint4*)d_ws;                              // 2 MiB
    float* sqm         = (float*)d_ws + (size_t)Bn * N * 16;        // +128 KiB

    pack_kernel<<<dim3(N / 256, Bn), 256, 0, stream>>>(X, Xp, sqm);
    gs_mfma<<<dim3(N / BM, Bn), BLK, 0, stream>>>(Xp, sqm, sigma, out);
}

// Round 4
// 555.649 us; speedup vs baseline: 1.0929x; 1.0929x over previous
//
#include <hip/hip_runtime.h>

// GaussianSoftmax: out[b,n,m] = softmax_m( exp( exp(-max(||x_n-x_m||^2,0)/sigma) ) )
// X: [8, 4096, 16] fp32, sigma: [1], out: [8, 4096, 4096] fp32 (512 MiB).
//
// R15 = R14's MFMA compute (harness-proven exact: hi/lo split-bf16, 2 mfma
// 16x16x32 per tile) + R13's store structure (bf16 e staged in LDS, then
// CONTIGUOUS 1-KiB-per-instruction nt stores). R14 regressed (250 us gs) from
// scattered 16x64B nt stores (half-line HBM writes); R13's contiguous stores
// ran at full write BW. Here: BM=16 rows/block, 16 waves, 128 KiB LDS;
// wave w stores row w. LDS granule-XOR swizzle (gp = gl ^ (row<<2)) makes the
// MFMA-layout ds_write_b64 conflict-free (min 4 words/bank) and the read side
// a contiguous-window permutation -> store stays one 1 KiB segment per inst.
// e in (1,2.72] bf16 RNE -> out err <=1.3e-6 (R13-proven, 10x under thresh).

typedef float v4f __attribute__((ext_vector_type(4)));
typedef short bf8 __attribute__((ext_vector_type(8)));

constexpr int Bn  = 8;
constexpr int N   = 4096;
constexpr int F   = 16;
constexpr int BM  = 16;            // softmax rows per block (= MFMA tile n)
constexpr int BLK = 1024;          // 16 waves
constexpr int NW  = BLK / 64;      // 16
constexpr int TPW = (N / 16) / NW; // 16 m-tiles per wave

__device__ __forceinline__ unsigned short f2bf(float x) {   // RNE
    unsigned int u = __float_as_uint(x);
    unsigned int r = (u + 0x7FFFu + ((u >> 16) & 1u)) >> 16;
    return (unsigned short)r;
}
__device__ __forceinline__ float bf2f(unsigned short h) {
    return __uint_as_float(((unsigned int)h) << 16);
}
__device__ __forceinline__ float uni(float x) {
    return __int_as_float(__builtin_amdgcn_readfirstlane(__float_as_int(x)));
}

__global__ __launch_bounds__(256)
void pack_kernel(const float* __restrict__ X, uint4* __restrict__ Xp,
                 float* __restrict__ sqm) {
    const int b = blockIdx.y;
    const int m = blockIdx.x * 256 + threadIdx.x;
    const float4* src = (const float4*)(X + ((size_t)b * N + m) * F);
    const float4 v0 = src[0], v1 = src[1], v2 = src[2], v3 = src[3];
    const float x[F] = {v0.x, v0.y, v0.z, v0.w, v1.x, v1.y, v1.z, v1.w,
                        v2.x, v2.y, v2.z, v2.w, v3.x, v3.y, v3.z, v3.w};
    float s = 0.f;
    #pragma unroll
    for (int f = 0; f < F; ++f) s = fmaf(x[f], x[f], s);
    sqm[(size_t)b * N + m] = s;

    uint4* dst = Xp + ((size_t)b * N + m) * 4;
    #pragma unroll
    for (int g = 0; g < 4; ++g) {
        unsigned int hi[4], lo[4];
        #pragma unroll
        for (int j = 0; j < 4; ++j) {
            const float xf = x[4 * g + j];
            const unsigned short h = f2bf(xf);
            hi[j] = h;
            lo[j] = f2bf(xf - bf2f(h));
        }
        uint4 c;
        c.x = hi[0] | (hi[1] << 16);
        c.y = hi[2] | (hi[3] << 16);
        c.z = lo[0] | (lo[1] << 16);
        c.w = lo[2] | (lo[3] << 16);
        dst[g] = c;
    }
}

union BfU { uint4 u; bf8 h; };

__global__ __launch_bounds__(BLK)
void gs_mfma(const uint4* __restrict__ Xp, const float* __restrict__ sqm,
             const float* __restrict__ sigma_p, float* __restrict__ out) {
    extern __shared__ char smem[];
    unsigned short (*lds_e)[N] = (unsigned short (*)[N])smem;       // 128 KiB
    float* red = (float*)(smem + (size_t)BM * N * 2);               // NW x BM

    const int tid  = threadIdx.x;
    const int w    = tid >> 6;
    const int lane = tid & 63;
    const int g    = lane >> 4;
    const int c    = lane & 15;
    const int b    = blockIdx.y;
    const int n0   = blockIdx.x * BM;

    const uint4* Xpb = Xp + (size_t)b * N * 4;
    const float* sqb = sqm + (size_t)b * N;

    // Block-constant B frags (n-side rows n0..n0+15), hi/lo and swapped.
    BfU b1; b1.u = Xpb[(size_t)(n0 + c) * 4 + g];
    BfU b2; b2.u = make_uint4(b1.u.z, b1.u.w, b1.u.x, b1.u.y);

    const float sqn_l = sqb[n0 + c];
    const float nis   = uni(-1.0f / sigma_p[0]);

    float psum = 0.f;

    #pragma unroll
    for (int t = 0; t < TPW; ++t) {
        const int m_tile = w * (TPW * 16) + t * 16;
        BfU a; a.u = Xpb[(size_t)(m_tile + c) * 4 + g];

        v4f acc = {0.f, 0.f, 0.f, 0.f};
        acc = __builtin_amdgcn_mfma_f32_16x16x32_bf16(a.h, b1.h, acc, 0, 0, 0);
        acc = __builtin_amdgcn_mfma_f32_16x16x32_bf16(a.h, b2.h, acc, 0, 0, 0);
        // acc[j] = inner(x_{m_tile+4g+j}, x_{n0+c})

        const v4f sm4 = *(const v4f*)(sqb + m_tile + 4 * g);
        float ex = __expf(__expf(fmaxf(fmaf(-2.f, acc.x, sqn_l + sm4.x), 0.f) * nis));
        float ey = __expf(__expf(fmaxf(fmaf(-2.f, acc.y, sqn_l + sm4.y), 0.f) * nis));
        float ez = __expf(__expf(fmaxf(fmaf(-2.f, acc.z, sqn_l + sm4.z), 0.f) * nis));
        float ew = __expf(__expf(fmaxf(fmaf(-2.f, acc.w, sqn_l + sm4.w), 0.f) * nis));

        ushort4 pk;
        pk.x = f2bf(ex); pk.y = f2bf(ey); pk.z = f2bf(ez); pk.w = f2bf(ew);
        // logical 4-elem granule -> physical via row-XOR swizzle (bits 2-5)
        const int gl = (m_tile >> 2) + g;
        const int gp = gl ^ (c << 2);
        *(ushort4*)&lds_e[c][4 * gp] = pk;    // b64, banks uniformly spread

        psum += (ex + ey) + (ez + ew);
    }

    // Row-sum for row n0+c: fold the 4 g-groups, then the 16 waves.
    psum += __shfl_xor(psum, 16, 64);
    psum += __shfl_xor(psum, 32, 64);
    if (lane < 16) red[w * BM + lane] = psum;
    __syncthreads();   // lds_e + red visible

    // Wave w handles softmax row w: total = sum over waves' partials.
    float tot = 0.f;
    #pragma unroll
    for (int w2 = 0; w2 < NW; ++w2) tot += red[w2 * BM + w];   // broadcast
    const float inv = uni(1.0f / tot);

    // Store row w: contiguous LDS read (conflict-free), XOR gives an
    // in-window lane permutation on the global address -> each instruction
    // covers one contiguous 1 KiB segment of the row (full 128B lines).
    float* rowp = out + ((size_t)b * N + n0 + w) * (size_t)N;
    #pragma unroll
    for (int k = 0; k < N / 4 / 64; ++k) {     // 16 iterations
        const int gp = 64 * k + lane;
        const int gl = gp ^ (w << 2);
        const ushort4 pk = *(const ushort4*)&lds_e[w][4 * gp];
        v4f v;
        v.x = bf2f(pk.x) * inv;
        v.y = bf2f(pk.y) * inv;
        v.z = bf2f(pk.z) * inv;
        v.w = bf2f(pk.w) * inv;
        __builtin_nontemporal_store(v, (v4f*)rowp + gl);
    }
}

extern "C" void kernel_launch(void* const* d_in, const int* in_sizes, int n_in,
                              void* d_out, int out_size, void* d_ws, size_t ws_size,
                              hipStream_t stream) {
    const float* X     = (const float*)d_in[0];
    const float* sigma = (const float*)d_in[1];
    float* out         = (float*)d_out;
    uint4* Xp          = (uint4*)d_ws;                              // 2 MiB
    float* sqm         = (float*)d_ws + (size_t)Bn * N * 16;        // +128 KiB

    const size_t lds_bytes = (size_t)BM * N * 2 + NW * BM * 4;      // 129 KiB
    pack_kernel<<<dim3(N / 256, Bn), 256, 0, stream>>>(X, Xp, sqm);
    gs_mfma<<<dim3(N / BM, Bn), BLK, lds_bytes, stream>>>(Xp, sqm, sigma, out);
}